// Round 12
// baseline (3634.391 us; speedup 1.0000x reference)
//
#include <hip/hip_runtime.h>
#include <hip/hip_bf16.h>
#include <math.h>

#define B_ 256
#define L_ 512
#define V_ 256
#define E_ 256
#define H_ 1024

typedef float  f32x4  __attribute__((ext_vector_type(4)));
typedef short  bf16x8 __attribute__((ext_vector_type(8)));
typedef unsigned int u32;
typedef unsigned char u8;

static __device__ __forceinline__ ushort f2bf(float v) {
    __hip_bfloat16 b = __float2bfloat16(v);
    return *reinterpret_cast<ushort*>(&b);
}

// fast tanh: 1 - 2/(exp(2z)+1); exact limits, ~1e-7 rel err
static __device__ __forceinline__ float ftanh(float z) {
    float e = __expf(2.f * z);
    return 1.f - 2.f / (e + 1.f);
}

// ---------- prep kernels (R11-proven) ----------
__global__ void k_transpose_bf16(const float* __restrict__ in, ushort* __restrict__ out,
                                 int R, int C) {
    __shared__ float tile[64][65];
    int bx = blockIdx.x, by = blockIdx.y;
    int tid = threadIdx.x;
    int g = tid >> 6, l = tid & 63;
    for (int i = 0; i < 16; ++i) {
        int r = g * 16 + i;
        tile[r][l] = in[(size_t)(by * 64 + r) * C + bx * 64 + l];
    }
    __syncthreads();
    for (int i = 0; i < 16; ++i) {
        int c = g * 16 + i;
        out[(size_t)(bx * 64 + c) * R + by * 64 + l] = f2bf(tile[l][c]);
    }
}

__global__ void k_f32_to_bf16(const float* __restrict__ in, ushort* __restrict__ out, int n) {
    int i = blockIdx.x * blockDim.x + threadIdx.x;
    if (i < n) out[i] = f2bf(in[i]);
}

__global__ void k_zero(u32* __restrict__ p, int n) {
    int i = blockIdx.x * blockDim.x + threadIdx.x;
    if (i < n) p[i] = 0u;
}

__global__ void k_proj(const float* __restrict__ emb, const float* __restrict__ We,
                       float* __restrict__ proj) {
    __shared__ float er[E_];
    int t = blockIdx.x;
    int h = blockIdx.y * 256 + threadIdx.x;
    er[threadIdx.x] = emb[t * E_ + threadIdx.x];
    __syncthreads();
    float acc = 0.f;
#pragma unroll 8
    for (int e = 0; e < E_; ++e) acc += er[e] * We[(size_t)e * H_ + h];
    proj[(size_t)t * H_ + h] = acc;
}

// ---------- chunked scan: per-wave K-sliced eager dataflow ----------
// 256 blocks x 128 threads (2 waves), 1 block/CU (LDS-padded). Block
// (rg=bid&7, cg=bid>>3); wave w owns h rows [rg*32+w*16,+16) x cols
// [cg*32,+32). Per step, a wave: polls the 32 per-producer-WAVE flags of its
// row half (one gather load per spin), then pipelines 32 A-frag loads (one
// dwordx4/lane/slice, direct from ring - no LDS panel) in 4 batches of 8,
// double-buffered with vmcnt(8) ladders feeding 64 MFMAs; tanh; wave-local
// stile; 16B stores; vmcnt(0); its own byte flag. ZERO block barriers in the
// loop - waves drift freely; S=65 no-reuse ring slots make drift safe within
// a 64-step chunk; kernel boundaries resync chunks (R11-proven).
__global__ __launch_bounds__(128, 1) void k_scan(
    const int* __restrict__ xs, const float* __restrict__ proj,
    const ushort* __restrict__ WhT, ushort* __restrict__ ring,
    float* __restrict__ final_h, u8* __restrict__ flags,
    int t0, int Tc, int S)
{
    __shared__ ushort lds_w[32 * 1024];   // W_h^T cols [c0,+32), swizzled (64KB)
    __shared__ ushort stile[2][16][32];   // per-wave h-tile repack (2KB)
    __shared__ char   pad_[20480];        // forces 1 block/CU (total >80KB)

    int tid = threadIdx.x;
    int w = tid >> 6, lane = tid & 63;
    int l15 = lane & 15, l4 = lane >> 4;
    int bid = blockIdx.x;
    int rg = bid & 7, cg = bid >> 3;
    int r0 = rg * 32, c0 = cg * 32;

    // keep pad_ alive (xs values are in [0,V); branch never taken, not provable)
    if (xs[0] == -2147483647) { pad_[tid] = 1; final_h[0] = pad_[tid]; }

    // --- W preload once per chunk (64KB, 128 threads x 32 chunks of 1KB)
    {
        const char* wsrc = (const char*)(WhT + (size_t)c0 * H_);
        char* wd = (char*)lds_w;
        for (int i = 0; i < 32; ++i) {
            int chunk = (w * 32 + i) * 1024;
            int o = chunk + lane * 16;
            int row = o >> 11, b = o & 2047;
            int so = row * 2048 + (b ^ ((row & 7) << 4));
            __builtin_amdgcn_global_load_lds(
                (const __attribute__((address_space(1))) void*)(wsrc + so),
                (__attribute__((address_space(3))) void*)(wd + chunk), 16, 0, 0);
        }
    }
    asm volatile("s_waitcnt vmcnt(0)" ::: "memory");
    __syncthreads();   // the ONLY block barrier in this kernel

    int as_ = (l15 & 7) << 4;
    const char* wb0 = (const char*)lds_w + (size_t)l15 * 2048;        // W cols c0+l15
    const char* wb1 = (const char*)lds_w + (size_t)(16 + l15) * 2048; // W cols c0+16+l15

#define ISSUE(BUF, BB) _Pragma("unroll") \
    for (int i_ = 0; i_ < 8; ++i_) \
        asm volatile("global_load_dwordx4 %0, %1, off sc0 sc1" \
                     : "=v"(BUF[i_]) : "v"(abase + ((BB) * 8 + i_) * 64) : "memory");
#define WAITV(N) do { asm volatile("s_waitcnt vmcnt(" #N ")" ::: "memory"); \
                      __builtin_amdgcn_sched_barrier(0); } while (0)
#define CONSUME(BUF, BB) _Pragma("unroll") \
    for (int i_ = 0; i_ < 8; ++i_) { \
        int kb_ = (((BB) * 8 + i_) * 32 + l4 * 8) * 2; \
        bf16x8 b0_ = *(const bf16x8*)(wb0 + (kb_ ^ as_)); \
        bf16x8 b1_ = *(const bf16x8*)(wb1 + (kb_ ^ as_)); \
        bf16x8 av_ = *(const bf16x8*)&BUF[i_]; \
        acc0 = __builtin_amdgcn_mfma_f32_16x16x32_bf16(av_, b0_, acc0, 0, 0, 0); \
        acc1 = __builtin_amdgcn_mfma_f32_16x16x32_bf16(av_, b1_, acc1, 0, 0, 0); \
    }

    for (int s = 0; s < Tc; ++s) {
        int t = t0 + s;

        // pv gather (plain cached loads, issued early; drained below)
        int xv[4];
#pragma unroll
        for (int j = 0; j < 4; ++j)
            xv[j] = xs[(r0 + w * 16 + l4 * 4 + j) * L_ + t];
        float pv0[4], pv1[4];
#pragma unroll
        for (int j = 0; j < 4; ++j) {
            pv0[j] = proj[(size_t)xv[j] * H_ + c0 + l15];
            pv1[j] = proj[(size_t)xv[j] * H_ + c0 + 16 + l15];
        }

        // poll the 32 producer-wave flags of this wave's row half
        if (s > 0) {
            const u8* fp = flags + (((size_t)t * 8 + rg) * 32 + lane) * 2 + w;
            u32 v = 1u;
            while (true) {
                if (lane < 32)
                    asm volatile("global_load_ubyte %0, %1, off sc0 sc1\n\t"
                                 "s_waitcnt vmcnt(0)" : "=v"(v) : "v"(fp) : "memory");
                if (__ballot(v != 0u) == ~0ull) break;
            }
        }
        asm volatile("s_waitcnt vmcnt(0)" ::: "memory");   // vmcnt=0 baseline (also s==0)
        __builtin_amdgcn_sched_barrier(0);

        // A-frag pipeline: rows r0+w*16+l15 of slot t%S, slice c -> offset c*64
        const char* abase = (const char*)(ring + (size_t)(t % S) * B_ * H_
                            + (size_t)(r0 + w * 16 + l15) * H_) + l4 * 16;
        f32x4 acc0 = {0.f, 0.f, 0.f, 0.f}, acc1 = {0.f, 0.f, 0.f, 0.f};
        f32x4 tvA[8], tvB[8];
        ISSUE(tvA, 0)
        ISSUE(tvB, 1)
        WAITV(8);
        CONSUME(tvA, 0)
        ISSUE(tvA, 2)
        WAITV(8);
        CONSUME(tvB, 1)
        ISSUE(tvB, 3)
        WAITV(8);
        CONSUME(tvA, 2)
        WAITV(0);
        CONSUME(tvB, 3)

        // tanh + wave-local stile
#pragma unroll
        for (int j = 0; j < 4; ++j) {
            float h0 = ftanh(acc0[j] + pv0[j]);
            float h1 = ftanh(acc1[j] + pv1[j]);
            stile[w][l4 * 4 + j][l15] = f2bf(h0);
            stile[w][l4 * 4 + j][16 + l15] = f2bf(h1);
            if (t == L_ - 1) {
                int grow = r0 + w * 16 + l4 * 4 + j;
                final_h[(size_t)grow * H_ + c0 + l15] = h0;
                final_h[(size_t)grow * H_ + c0 + 16 + l15] = h1;
            }
        }
        asm volatile("s_waitcnt lgkmcnt(0)" ::: "memory");   // stile visible wave-wide
        __builtin_amdgcn_sched_barrier(0);

        // coalesced 16B stores of the 16x32 tile -> slot (t+1)%S, drain, flag
        {
            int row = lane >> 2, seg = lane & 3;
            f32x4 d = *(const f32x4*)&stile[w][row][seg * 8];
            char* dst = (char*)(ring + (size_t)((t + 1) % S) * B_ * H_
                                + (size_t)(r0 + w * 16 + row) * H_ + c0 + seg * 8);
            asm volatile("global_store_dwordx4 %0, %1, off sc0 sc1"
                         :: "v"(dst), "v"(d) : "memory");
        }
        asm volatile("s_waitcnt vmcnt(0)" ::: "memory");     // data at coherence point
        if (lane == 0) {
            u8* fdst = flags + (((size_t)(t + 1) * 8 + rg) * 32 + cg) * 2 + w;
            u32 one = 1u;
            asm volatile("global_store_byte %0, %1, off sc0 sc1"
                         :: "v"(fdst), "v"(one) : "memory");
        }
        // no block barrier: waves drift; slot no-reuse within chunk makes it safe
    }
#undef ISSUE
#undef WAITV
#undef CONSUME
}

// ---------- per-chunk logits GEMM (R11-proven) ----------
__global__ __launch_bounds__(256, 1) void k_logits(
    const ushort* __restrict__ ring, const ushort* __restrict__ WoT,
    float* __restrict__ logits, int t0, int S)
{
    __shared__ ushort Ap[64 * 1024];   // 128KB, swizzled
    int tid = threadIdx.x;
    int w = tid >> 6, lane = tid & 63;
    int l15 = lane & 15, l4 = lane >> 4;
    int bid = blockIdx.x;
    int tl = bid >> 2, q = bid & 3;
    int t = t0 + tl, slot = (t + 1) % S;

    {
        const char* asrc = (const char*)(ring + (size_t)slot * B_ * H_
                                         + (size_t)(q * 64) * H_);
        char* ad = (char*)Ap;
        for (int i = 0; i < 32; ++i) {
            int chunk = (w * 32 + i) * 1024;
            int o = chunk + lane * 16;
            int row = o >> 11, b = o & 2047;
            int so = row * 2048 + (b ^ ((row & 7) << 4));
            __builtin_amdgcn_global_load_lds(
                (const __attribute__((address_space(1))) void*)(asrc + so),
                (__attribute__((address_space(3))) void*)(ad + chunk), 16, 0, 0);
        }
    }
    asm volatile("s_waitcnt vmcnt(0)" ::: "memory");
    __syncthreads();

    int arow = w * 16 + l15;
    const char* ha = (const char*)Ap + (size_t)arow * 2048;
    int as_ = (arow & 7) << 4;
    bf16x8 af[32];
#pragma unroll
    for (int kk = 0; kk < 32; ++kk) {
        int kb = (kk * 32 + l4 * 8) * 2;
        af[kk] = *(const bf16x8*)(ha + (kb ^ as_));
    }
    f32x4 acc[16];
#pragma unroll
    for (int vs = 0; vs < 16; ++vs) acc[vs] = (f32x4){0.f, 0.f, 0.f, 0.f};
    const ushort* wob = WoT + (size_t)l15 * H_ + l4 * 8;
#pragma unroll
    for (int kk = 0; kk < 32; ++kk) {
#pragma unroll
        for (int vs = 0; vs < 16; ++vs) {
            bf16x8 bfr = *(const bf16x8*)(wob + (size_t)(vs * 16) * H_ + kk * 32);
            acc[vs] = __builtin_amdgcn_mfma_f32_16x16x32_bf16(af[kk], bfr, acc[vs], 0, 0, 0);
        }
    }
#pragma unroll
    for (int vs = 0; vs < 16; ++vs)
#pragma unroll
        for (int j = 0; j < 4; ++j) {
            int brow = q * 64 + w * 16 + l4 * 4 + j;
            logits[(size_t)brow * (L_ * V_) + (size_t)t * V_ + vs * 16 + l15] = acc[vs][j];
        }
}

extern "C" void kernel_launch(void* const* d_in, const int* in_sizes, int n_in,
                              void* d_out, int out_size, void* d_ws, size_t ws_size,
                              hipStream_t stream)
{
    const int*   x   = (const int*)d_in[0];
    const float* hid = (const float*)d_in[1];
    const float* emb = (const float*)d_in[2];
    const float* We  = (const float*)d_in[3];
    const float* Wh  = (const float*)d_in[4];
    const float* Wo  = (const float*)d_in[5];

    float* logits  = (float*)d_out;                       // [B][L][V] f32
    float* final_h = logits + (size_t)B_ * L_ * V_;       // [B][H] f32

    char* ws = (char*)d_ws;
    float*  proj  = (float*)(ws);                                  // 1 MB   @0
    ushort* WhT   = (ushort*)(ws + (1u << 20));                    // 2 MB   @1MB
    ushort* WoT   = (ushort*)(ws + 3u * (1u << 20));               // 0.5 MB @3MB
    u8*     flags = (u8*)(ws + 3u * (1u << 20) + (1u << 19));      // 263 KB @3.5MB
    const size_t RING_OFF = 4u * (1u << 20);                       // 4MB
    ushort* ring  = (ushort*)(ws + RING_OFF);
    const size_t SLOT = (size_t)B_ * H_ * 2u;                      // 512 KB

    int S = (int)(ws_size > RING_OFF ? (ws_size - RING_OFF) / SLOT : 0);
    if (S > 65) S = 65;
    if (S < 2)  S = 2;

    // prep
    const int FW = 513 * 8 * 32 * 2 / 4;   // flag words
    k_zero<<<dim3((FW + 255) / 256), 256, 0, stream>>>((u32*)flags, FW);
    k_transpose_bf16<<<dim3(16, 16), 256, 0, stream>>>(Wh, WhT, H_, H_);
    k_transpose_bf16<<<dim3(4, 16),  256, 0, stream>>>(Wo, WoT, H_, V_);
    k_f32_to_bf16<<<dim3(1024), 256, 0, stream>>>(hid, ring, B_ * H_);   // H_0 -> slot 0
    k_proj<<<dim3(256, 4), 256, 0, stream>>>(emb, We, proj);

    // chunked scan + per-chunk logits GEMM
    int T = S - 1;
    for (int t0 = 0; t0 < L_; t0 += T) {
        int Tc = (L_ - t0 < T) ? (L_ - t0) : T;
        k_scan<<<dim3(256), 128, 0, stream>>>(x, proj, WhT, ring,
                                              final_h, flags, t0, Tc, S);
        k_logits<<<dim3(4 * Tc), 256, 0, stream>>>(ring, WoT, logits, t0, S);
    }
}